// Round 7
// baseline (51.434 us; speedup 1.0000x reference)
//
#include <hip/hip_runtime.h>
#include <hip/hip_bf16.h>

// Exact Gaussian lattice filter: out = (W - I) @ U, W_ij = exp(-0.5*max(d2,0))
// N=8192, D=5 features, C=21 channels.
//
// R7: R5's verified skeleton (32x32x16 bf16 MFMA, layout m74/m101; fp32
// exponent; LDS B-pack; NO inline asm anywhere) with:
//  - bf16 pack via scalar __float2bfloat16 casts (m240: compiler codegen for
//    f32->bf16 is good; R5's integer RNE was ~40% of VALU work; R6's hand-asm
//    v_pk/cvt_pk experiments miscompiled -> absmax 2752, reverted)
//  - occupancy: JWIN 128 -> LDS 12.3KB, __launch_bounds__(256,8),
//    JSPLIT 32 -> grid 64x32 = 2048 blocks = 8/CU (R5: 4/CU, occ 27%)

#define NN 8192
#define CC 21
#define DD 5
#define BLOCK 256
#define IBLK 128                // 4 waves x 32 rows
#define NIB (NN / IBLK)         // 64
#define JSPLIT 32
#define JCHUNK (NN / JSPLIT)    // 256
#define JWIN 128
#define NWIN (JCHUNK / JWIN)    // 2
#define JSTEP 16
#define NSTEP (JWIN / JSTEP)    // 8

typedef __attribute__((ext_vector_type(8)))  short    bf16x8;
typedef __attribute__((ext_vector_type(16))) float    f32x16;
typedef __attribute__((ext_vector_type(4)))  unsigned u32x4;

__device__ __forceinline__ short bf16_of(float x) {
    __hip_bfloat16 h = __float2bfloat16(x);   // RNE, compiler-lowered
    short s;
    __builtin_memcpy(&s, &h, 2);
    return s;
}

__global__ __launch_bounds__(BLOCK, 8)
void lattice_gauss_mfma32(const float* __restrict__ U,
                          const float* __restrict__ ref,
                          float* __restrict__ out) {
    // LDS: [0, 4096)    f-staging, 32B per j: {L*f0..L*f3},{L*f4, a_j, pad, pad}
    //      [4096,12288) B-fragments: 16B per (step s, frag-lane ln) at (s*64+ln)*16
    __shared__ __align__(16) char smem[JWIN * 32 + NSTEP * 64 * 16];
    char* sFm = smem;
    char* sB  = smem + JWIN * 32;

    const int t    = threadIdx.x;
    const int lane = t & 63;
    const int wv   = t >> 6;           // wave 0..3
    const int h    = lane >> 5;        // k-half 0..1
    const int m    = lane & 31;        // A row / D col (channel)
    const int iblock = blockIdx.x;
    const int jc     = blockIdx.y;
    const float L  = 1.4426950408889634f;    // log2(e)
    const float NH = -0.7213475204444817f;   // -0.5*log2(e)

    const int ibase = iblock * IBLK + wv * 32;

    // ---- per-lane i-row features (row m of this wave's 32-row tile) ----
    const float* fiP = ref + (size_t)(ibase + m) * DD;
    const float fi0 = fiP[0], fi1 = fiP[1], fi2 = fiP[2], fi3 = fiP[3], fi4 = fiP[4];
    const float ai = NH * (fi0*fi0 + fi1*fi1 + fi2*fi2 + fi3*fi3 + fi4*fi4);

    // ---- accumulator: D[row][col=m]; fold -U at jc==0 ----
    f32x16 acc;
    #pragma unroll
    for (int r = 0; r < 16; ++r) acc[r] = 0.f;
    if (jc == 0 && m < CC) {
        #pragma unroll
        for (int r = 0; r < 16; ++r) {
            const int row = (r & 3) + 8 * (r >> 2) + 4 * h;
            acc[r] = -U[(size_t)(ibase + row) * CC + m];
        }
    }

    for (int win = 0; win < NWIN; ++win) {
        const int jwbase = jc * JCHUNK + win * JWIN;
        __syncthreads();   // protect smem reuse across windows

        // ---- stage f_j: thread t (<128) -> j = t ----
        if (t < JWIN) {
            const int j = t;
            const float* fj = ref + (size_t)(jwbase + j) * DD;
            const float f0 = fj[0], f1 = fj[1], f2 = fj[2], f3 = fj[3], f4 = fj[4];
            const float sq = f0*f0 + f1*f1 + f2*f2 + f3*f3 + f4*f4;
            char* pw = sFm + j * 32;
            *(float4*)pw        = make_float4(L*f0, L*f1, L*f2, L*f3);
            *(float2*)(pw + 16) = make_float2(L*f4, NH * sq);
        }

        // ---- pack B-fragments: slot q = s*64 + ln, 2 slots per thread ----
        // B[k][n]: n = ln&31 (channel), k-slot = (ln>>5)*8 + e
        //          -> j = jwbase + s*16 + k-slot
        for (int q = t; q < NSTEP * 64; q += BLOCK) {
            const int s_ = q >> 6;
            const int ln = q & 63;
            const int c  = ln & 31;
            const int jb = jwbase + s_ * JSTEP + (ln >> 5) * 8;
            short v[8] __attribute__((aligned(16))) = {0,0,0,0,0,0,0,0};
            if (c < CC) {
                const float* up = U + (size_t)jb * CC + c;
                #pragma unroll
                for (int e = 0; e < 8; ++e) v[e] = bf16_of(up[e * CC]);
            }
            u32x4 pk;
            __builtin_memcpy(&pk, v, 16);
            *(u32x4*)(sB + (size_t)q * 16) = pk;
        }
        __syncthreads();

        // ---- compute: 8 steps of 16 js ----
        for (int s = 0; s < NSTEP; ++s) {
            const u32x4 braw = *(const u32x4*)(sB + ((s * 64 + lane) * 16));
            const bf16x8 bfrag = __builtin_bit_cast(bf16x8, braw);

            short av[8] __attribute__((aligned(16)));
            #pragma unroll
            for (int e = 0; e < 8; ++e) {
                const char* pr = sFm + (s * JSTEP + h * 8 + e) * 32;
                const float4 fA = *(const float4*)pr;
                const float2 fB = *(const float2*)(pr + 16);
                float x = ai + fB.y;
                x = fmaf(fi0, fA.x, x);
                x = fmaf(fi1, fA.y, x);
                x = fmaf(fi2, fA.z, x);
                x = fmaf(fi3, fA.w, x);
                x = fmaf(fi4, fB.x, x);
                x = fminf(x, 0.f);
                av[e] = bf16_of(__builtin_amdgcn_exp2f(x));
            }
            bf16x8 afrag;
            __builtin_memcpy(&afrag, av, 16);

            acc = __builtin_amdgcn_mfma_f32_32x32x16_bf16(afrag, bfrag, acc, 0, 0, 0);
        }
    }

    // ---- epilogue: D col = m (channel), row = (r&3) + 8*(r>>2) + 4*h ----
    if (m < CC) {
        #pragma unroll
        for (int r = 0; r < 16; ++r) {
            const int row = (r & 3) + 8 * (r >> 2) + 4 * h;
            unsafeAtomicAdd(&out[(size_t)(ibase + row) * CC + m], acc[r]);
        }
    }
}

extern "C" void kernel_launch(void* const* d_in, const int* in_sizes, int n_in,
                              void* d_out, int out_size, void* d_ws, size_t ws_size,
                              hipStream_t stream) {
    const float* U   = (const float*)d_in[0];
    const float* ref = (const float*)d_in[1];
    float* out = (float*)d_out;

    hipMemsetAsync(out, 0, (size_t)out_size * sizeof(float), stream);

    dim3 grid(NIB, JSPLIT);
    lattice_gauss_mfma32<<<grid, BLOCK, 0, stream>>>(U, ref, out);
}

// Round 8
// 44.069 us; speedup vs baseline: 1.1671x; 1.1671x over previous
//
#include <hip/hip_runtime.h>
#include <hip/hip_bf16.h>

// Exact Gaussian lattice filter: out = (W - I) @ U, W_ij = exp(-0.5*max(d2,0))
// N=8192, D=5 features, C=21 channels.
//
// R8: both contractions on MFMA. R7 was LDS-issue-bound (17 ds_reads/step,
// ~43us of LDS issue = measured time). Now the D=5 dot products run on the
// matrix core via a hi/lo bf16 split (error ~2^-18: only lo*lo dropped):
//   A_j = {hj0..4, lj0..4, hj0..4, 0}, B_i = {Lhi0..4, Lhi0..4, Llo0..4, 0}
//   S = mfma_32x32x16(A_j, B_i) = L * (fi . fj)  (fp32 accum)
// S arrives with lane = col i, rows = j -- exactly the A-fragment shape for
// the W@U MFMAs, with U B-fragments packed under the matching permutation
// sigma(g,e) = (e&3) + 8*(e>>2) + 4g. LDS per 32 js per wave: 7 reads
// (1 F-frag + 4 aj quads (2-way broadcast) + 2 U-frags) vs R7's 34.
// x = ai + aj + S (all fp32), w = exp2(min(x,0)); no inline asm anywhere.

#define NN 8192
#define CC 21
#define DD 5
#define BLOCK 256
#define IBLK 128                // 4 waves x 32 rows
#define NIB (NN / IBLK)         // 64
#define JSPLIT 32
#define JCHUNK (NN / JSPLIT)    // 256 (staged once, no window loop)
#define NTILE (JCHUNK / 32)     // 8 j-tiles of 32

typedef __attribute__((ext_vector_type(8)))  short    bf16x8;
typedef __attribute__((ext_vector_type(16))) float    f32x16;
typedef __attribute__((ext_vector_type(4)))  unsigned u32x4;

__device__ __forceinline__ short bf16s(float x) {
    __hip_bfloat16 h = __float2bfloat16(x);   // RNE, compiler-lowered
    short s; __builtin_memcpy(&s, &h, 2); return s;
}
__device__ __forceinline__ float bf16f(short s) {
    __hip_bfloat16 h; __builtin_memcpy(&h, &s, 2); return __bfloat162float(h);
}

__global__ __launch_bounds__(BLOCK, 6)
void lattice_gauss_s2(const float* __restrict__ U,
                      const float* __restrict__ ref,
                      float* __restrict__ out) {
    // LDS: [0, 8192)        F_j A-frags: 16B per (tile, frag-lane)
    //      [8192, 9216)     aj = -0.5*L*||f_j||^2, fp32 per j
    //      [9216, 25600)    U B-frags: 16B per (tile, ktile, frag-lane)
    __shared__ __align__(16) char smem[NTILE * 64 * 16 + JCHUNK * 4 + NTILE * 2 * 64 * 16];
    char*  sFA = smem;
    float* sAJ = (float*)(smem + NTILE * 64 * 16);
    char*  sUB = smem + NTILE * 64 * 16 + JCHUNK * 4;

    const int t    = threadIdx.x;
    const int lane = t & 63;
    const int wv   = t >> 6;           // wave 0..3
    const int h    = lane >> 5;        // k-half / D-row-half selector
    const int m    = lane & 31;        // i-row within wave tile / D col
    const int iblock = blockIdx.x;
    const int jc     = blockIdx.y;
    const float L  = 1.4426950408889634f;    // log2(e)
    const float NH = -0.7213475204444817f;   // -0.5*log2(e)

    const int ibase  = iblock * IBLK + wv * 32;
    const int jwbase = jc * JCHUNK;

    // ---- stage j-chunk: thread t -> j = jwbase + t ----
    {
        const float* fj = ref + (size_t)(jwbase + t) * DD;
        const float f0 = fj[0], f1 = fj[1], f2 = fj[2], f3 = fj[3], f4 = fj[4];
        sAJ[t] = NH * (f0*f0 + f1*f1 + f2*f2 + f3*f3 + f4*f4);
        short hj[5], lj[5];
        const float ff[5] = {f0, f1, f2, f3, f4};
        #pragma unroll
        for (int d = 0; d < DD; ++d) {
            hj[d] = bf16s(ff[d]);
            lj[d] = bf16s(ff[d] - bf16f(hj[d]));
        }
        short s0[8] __attribute__((aligned(16))) =
            {hj[0], hj[1], hj[2], hj[3], hj[4], lj[0], lj[1], lj[2]};
        short s1[8] __attribute__((aligned(16))) =
            {lj[3], lj[4], hj[0], hj[1], hj[2], hj[3], hj[4], 0};
        char* base = sFA + (((t >> 5) * 64) + (t & 31)) * 16;
        u32x4 p0, p1;
        __builtin_memcpy(&p0, s0, 16); __builtin_memcpy(&p1, s1, 16);
        *(u32x4*)base         = p0;
        *(u32x4*)(base + 512) = p1;   // frag-lane +32
    }

    // ---- stage U B-frags: slot q = (tile*2+kt)*64 + ln, 4 per thread ----
    // B k-slot (g,e) -> j-offset sigma = (e&3) + 8*(e>>2) + 4g (+ kt*16)
    for (int q = t; q < NTILE * 2 * 64; q += BLOCK) {
        const int ln = q & 63, kt = (q >> 6) & 1, tile = q >> 7;
        const int c = ln & 31, g = ln >> 5;
        short v[8] __attribute__((aligned(16))) = {0,0,0,0,0,0,0,0};
        if (c < CC) {
            #pragma unroll
            for (int e = 0; e < 8; ++e) {
                const int j = jwbase + tile * 32 + kt * 16 + (e & 3) + 8 * (e >> 2) + 4 * g;
                v[e] = bf16s(U[(size_t)j * CC + c]);
            }
        }
        u32x4 pk; __builtin_memcpy(&pk, v, 16);
        *(u32x4*)(sUB + (size_t)q * 16) = pk;
    }

    // ---- per-lane i-row: ai and the L-scaled hi/lo B-fragment (registers) ----
    const float* fiP = ref + (size_t)(ibase + m) * DD;
    const float fi0 = fiP[0], fi1 = fiP[1], fi2 = fiP[2], fi3 = fiP[3], fi4 = fiP[4];
    const float ai = NH * (fi0*fi0 + fi1*fi1 + fi2*fi2 + fi3*fi3 + fi4*fi4);
    bf16x8 bfi;
    {
        const float sf[5] = {L*fi0, L*fi1, L*fi2, L*fi3, L*fi4};
        short hi_[5], lo_[5];
        #pragma unroll
        for (int d = 0; d < DD; ++d) {
            hi_[d] = bf16s(sf[d]);
            lo_[d] = bf16s(sf[d] - bf16f(hi_[d]));
        }
        // B_i layout k0..15: {Lh0..Lh4, Lh0..Lh4, Ll0..Ll4, 0}
        // g=0 holds k0..7, g=1 holds k8..15 (h selects per lane)
        short bv[8] __attribute__((aligned(16)));
        bv[0] = h ? hi_[3] : hi_[0];
        bv[1] = h ? hi_[4] : hi_[1];
        bv[2] = h ? lo_[0] : hi_[2];
        bv[3] = h ? lo_[1] : hi_[3];
        bv[4] = h ? lo_[2] : hi_[4];
        bv[5] = h ? lo_[3] : hi_[0];
        bv[6] = h ? lo_[4] : hi_[1];
        bv[7] = h ? (short)0 : hi_[2];
        __builtin_memcpy(&bfi, bv, 16);
    }

    // ---- accumulator: D[row=i][col=c]; fold -U at jc==0 ----
    f32x16 acc;
    #pragma unroll
    for (int r = 0; r < 16; ++r) acc[r] = 0.f;
    if (jc == 0 && m < CC) {
        #pragma unroll
        for (int r = 0; r < 16; ++r) {
            const int row = (r & 3) + 8 * (r >> 2) + 4 * h;
            acc[r] = -U[(size_t)(ibase + row) * CC + m];
        }
    }
    __syncthreads();

    // ---- main loop: 8 tiles of 32 js ----
    for (int tile = 0; tile < NTILE; ++tile) {
        // S = L * (fi . fj), lane = col i (m), rows = j(r,h) = (r&3)+8*(r>>2)+4h
        const u32x4 fr = *(const u32x4*)(sFA + (tile * 64 + lane) * 16);
        f32x16 sacc;
        #pragma unroll
        for (int r = 0; r < 16; ++r) sacc[r] = 0.f;
        sacc = __builtin_amdgcn_mfma_f32_32x32x16_bf16(
            __builtin_bit_cast(bf16x8, fr), bfi, sacc, 0, 0, 0);

        // aj for this lane's 16 j rows: 4x float4, 2-way broadcast reads
        const float* ajp = sAJ + tile * 32 + 4 * h;
        float aqf[16] __attribute__((aligned(16)));
        *(float4*)&aqf[0]  = *(const float4*)(ajp);
        *(float4*)&aqf[4]  = *(const float4*)(ajp + 8);
        *(float4*)&aqf[8]  = *(const float4*)(ajp + 16);
        *(float4*)&aqf[12] = *(const float4*)(ajp + 24);

        short wv16[16] __attribute__((aligned(16)));
        #pragma unroll
        for (int r = 0; r < 16; ++r) {
            float x = (ai + aqf[r]) + sacc[r];
            x = fminf(x, 0.f);
            wv16[r] = bf16s(__builtin_amdgcn_exp2f(x));
        }
        bf16x8 a0, a1;
        __builtin_memcpy(&a0, &wv16[0], 16);
        __builtin_memcpy(&a1, &wv16[8], 16);

        const u32x4 b0 = *(const u32x4*)(sUB + ((tile * 2 + 0) * 64 + lane) * 16);
        const u32x4 b1 = *(const u32x4*)(sUB + ((tile * 2 + 1) * 64 + lane) * 16);

        acc = __builtin_amdgcn_mfma_f32_32x32x16_bf16(
            a0, __builtin_bit_cast(bf16x8, b0), acc, 0, 0, 0);
        acc = __builtin_amdgcn_mfma_f32_32x32x16_bf16(
            a1, __builtin_bit_cast(bf16x8, b1), acc, 0, 0, 0);
    }

    // ---- epilogue: D col = m (channel), row = (r&3) + 8*(r>>2) + 4*h ----
    if (m < CC) {
        #pragma unroll
        for (int r = 0; r < 16; ++r) {
            const int row = (r & 3) + 8 * (r >> 2) + 4 * h;
            unsafeAtomicAdd(&out[(size_t)(ibase + row) * CC + m], acc[r]);
        }
    }
}

extern "C" void kernel_launch(void* const* d_in, const int* in_sizes, int n_in,
                              void* d_out, int out_size, void* d_ws, size_t ws_size,
                              hipStream_t stream) {
    const float* U   = (const float*)d_in[0];
    const float* ref = (const float*)d_in[1];
    float* out = (float*)d_out;

    hipMemsetAsync(out, 0, (size_t)out_size * sizeof(float), stream);

    dim3 grid(NIB, JSPLIT);
    lattice_gauss_s2<<<grid, BLOCK, 0, stream>>>(U, ref, out);
}

// Round 9
// 26.603 us; speedup vs baseline: 1.9334x; 1.6566x over previous
//
#include <hip/hip_runtime.h>
#include <hip/hip_bf16.h>

// Exact Gaussian lattice filter: out = (W - I) @ U, W_ij = exp(-0.5*max(d2,0))
// N=8192, D=5 features, C=21 channels.
//
// R9: R8's verified numerics (hi/lo bf16 S-MFMA for fi.fj, fp32 exponent,
// bf16 W@U MFMA, layouts m74/m101) with restructured orchestration:
//  - pack kernel pre-packs F-frags (256KB) + U-frags (512KB) into d_ws once
//  - main kernel: block=1024thr (16 waves) owns 32 i-rows; waves split the
//    256 j-tiles; per tile: 3 coalesced global b128 frag loads, NO main-loop
//    barriers, NO atomics, NO memset (out fully overwritten by plain stores)
//  - deterministic in-LDS 16-way reduce, out = sum(acc) - U

#define NN 8192
#define CC 21
#define DD 5
#define NTILE_G (NN / 32)       // 256 j-tiles
#define ROWS 32                 // i-rows per block
#define NBLK (NN / ROWS)        // 256 blocks
#define MAINT 1024              // 16 waves
#define NWAVE 16
#define TPW (NTILE_G / NWAVE)   // 16 tiles per wave

#define F_OFF 0
#define U_OFF (NTILE_G * 64 * 16)   // 262144 B

typedef __attribute__((ext_vector_type(8)))  short    bf16x8;
typedef __attribute__((ext_vector_type(16))) float    f32x16;
typedef __attribute__((ext_vector_type(4)))  unsigned u32x4;

__device__ __forceinline__ short bf16s(float x) {
    __hip_bfloat16 h = __float2bfloat16(x);   // RNE, compiler-lowered
    short s; __builtin_memcpy(&s, &h, 2); return s;
}
__device__ __forceinline__ float bf16f(short s) {
    __hip_bfloat16 h; __builtin_memcpy(&h, &s, 2); return __bfloat162float(h);
}

// ---- pack kernel: F-frags then U-frags into ws ----
__global__ __launch_bounds__(256)
void pack_frags(const float* __restrict__ U, const float* __restrict__ ref,
                char* __restrict__ ws) {
    const int q = blockIdx.x * 256 + threadIdx.x;
    if (q < NTILE_G * 64) {
        // F-frag slot: tile = q>>6, frag-lane ln = q&63, j = tile*32 + (ln&31)
        const int tile = q >> 6, ln = q & 63;
        const int j = tile * 32 + (ln & 31);
        const float* fj = ref + (size_t)j * DD;
        short h_[5], l_[5];
        #pragma unroll
        for (int d = 0; d < DD; ++d) {
            const float f = fj[d];
            h_[d] = bf16s(f);
            l_[d] = bf16s(f - bf16f(h_[d]));
        }
        short v[8] __attribute__((aligned(16)));
        if (ln < 32) {
            v[0]=h_[0]; v[1]=h_[1]; v[2]=h_[2]; v[3]=h_[3];
            v[4]=h_[4]; v[5]=l_[0]; v[6]=l_[1]; v[7]=l_[2];
        } else {
            v[0]=l_[3]; v[1]=l_[4]; v[2]=h_[0]; v[3]=h_[1];
            v[4]=h_[2]; v[5]=h_[3]; v[6]=h_[4]; v[7]=0;
        }
        u32x4 pk; __builtin_memcpy(&pk, v, 16);
        *(u32x4*)(ws + F_OFF + (size_t)q * 16) = pk;
    } else {
        // U-frag slot: qu = q - 16384: tile=qu>>7, kt=(qu>>6)&1, ln=qu&63
        const int qu = q - NTILE_G * 64;
        const int ln = qu & 63, kt = (qu >> 6) & 1, tile = qu >> 7;
        const int c = ln & 31, g = ln >> 5;
        short v[8] __attribute__((aligned(16))) = {0,0,0,0,0,0,0,0};
        if (c < CC) {
            #pragma unroll
            for (int e = 0; e < 8; ++e) {
                const int j = tile * 32 + kt * 16 + (e & 3) + 8 * (e >> 2) + 4 * g;
                v[e] = bf16s(U[(size_t)j * CC + c]);
            }
        }
        u32x4 pk; __builtin_memcpy(&pk, v, 16);
        *(u32x4*)(ws + U_OFF + (size_t)qu * 16) = pk;
    }
}

// ---- main kernel ----
__global__ __launch_bounds__(MAINT, 4)
void lattice_main(const float* __restrict__ U, const float* __restrict__ ref,
                  const char* __restrict__ ws, float* __restrict__ out) {
    // LDS: [0,32768) aj[8192] during main loop; [0,65536) reduce buffer after
    __shared__ __align__(16) char smem[65536];
    float* ajb = (float*)smem;
    float* red = (float*)smem;   // [16][32][32] f32

    const int t    = threadIdx.x;
    const int lane = t & 63;
    const int wv   = t >> 6;        // wave 0..15
    const int h    = lane >> 5;
    const int m    = lane & 31;
    const int ibase = blockIdx.x * ROWS;
    const float L  = 1.4426950408889634f;    // log2(e)
    const float NH = -0.7213475204444817f;   // -0.5*log2(e)

    // ---- stage aj for ALL js (once per block) ----
    for (int j = t; j < NN; j += MAINT) {
        const float* fj = ref + (size_t)j * DD;
        const float f0 = fj[0], f1 = fj[1], f2 = fj[2], f3 = fj[3], f4 = fj[4];
        ajb[j] = NH * (f0*f0 + f1*f1 + f2*f2 + f3*f3 + f4*f4);
    }

    // ---- per-lane i-row: ai and L-scaled hi/lo B-fragment (same as R8) ----
    const float* fiP = ref + (size_t)(ibase + m) * DD;
    const float fi0 = fiP[0], fi1 = fiP[1], fi2 = fiP[2], fi3 = fiP[3], fi4 = fiP[4];
    const float ai = NH * (fi0*fi0 + fi1*fi1 + fi2*fi2 + fi3*fi3 + fi4*fi4);
    bf16x8 bfi;
    {
        const float sf[5] = {L*fi0, L*fi1, L*fi2, L*fi3, L*fi4};
        short hi_[5], lo_[5];
        #pragma unroll
        for (int d = 0; d < DD; ++d) {
            hi_[d] = bf16s(sf[d]);
            lo_[d] = bf16s(sf[d] - bf16f(hi_[d]));
        }
        short bv[8] __attribute__((aligned(16)));
        bv[0] = h ? hi_[3] : hi_[0];
        bv[1] = h ? hi_[4] : hi_[1];
        bv[2] = h ? lo_[0] : hi_[2];
        bv[3] = h ? lo_[1] : hi_[3];
        bv[4] = h ? lo_[2] : hi_[4];
        bv[5] = h ? lo_[3] : hi_[0];
        bv[6] = h ? lo_[4] : hi_[1];
        bv[7] = h ? (short)0 : hi_[2];
        __builtin_memcpy(&bfi, bv, 16);
    }

    f32x16 acc;
    #pragma unroll
    for (int r = 0; r < 16; ++r) acc[r] = 0.f;

    __syncthreads();   // aj ready

    const char* Fws = ws + F_OFF;
    const char* Uws = ws + U_OFF;

    // ---- main loop: this wave's 16 j-tiles, no barriers ----
    #pragma unroll 2
    for (int s = 0; s < TPW; ++s) {
        const int tile = wv * TPW + s;
        const u32x4 fr = *(const u32x4*)(Fws + ((size_t)(tile * 64 + lane)) * 16);
        const u32x4 b0 = *(const u32x4*)(Uws + ((size_t)((tile * 2 + 0) * 64 + lane)) * 16);
        const u32x4 b1 = *(const u32x4*)(Uws + ((size_t)((tile * 2 + 1) * 64 + lane)) * 16);

        f32x16 sacc;
        #pragma unroll
        for (int r = 0; r < 16; ++r) sacc[r] = 0.f;
        sacc = __builtin_amdgcn_mfma_f32_32x32x16_bf16(
            __builtin_bit_cast(bf16x8, fr), bfi, sacc, 0, 0, 0);

        const float* ajp = ajb + tile * 32 + 4 * h;
        float aqf[16] __attribute__((aligned(16)));
        *(float4*)&aqf[0]  = *(const float4*)(ajp);
        *(float4*)&aqf[4]  = *(const float4*)(ajp + 8);
        *(float4*)&aqf[8]  = *(const float4*)(ajp + 16);
        *(float4*)&aqf[12] = *(const float4*)(ajp + 24);

        short wv16[16] __attribute__((aligned(16)));
        #pragma unroll
        for (int r = 0; r < 16; ++r) {
            float x = (ai + aqf[r]) + sacc[r];
            x = fminf(x, 0.f);
            wv16[r] = bf16s(__builtin_amdgcn_exp2f(x));
        }
        bf16x8 a0, a1;
        __builtin_memcpy(&a0, &wv16[0], 16);
        __builtin_memcpy(&a1, &wv16[8], 16);

        acc = __builtin_amdgcn_mfma_f32_32x32x16_bf16(
            a0, __builtin_bit_cast(bf16x8, b0), acc, 0, 0, 0);
        acc = __builtin_amdgcn_mfma_f32_32x32x16_bf16(
            a1, __builtin_bit_cast(bf16x8, b1), acc, 0, 0, 0);
    }

    __syncthreads();   // all waves done with ajb; reuse LDS for reduce

    // ---- write partials: red[wv][row][m] ----
    #pragma unroll
    for (int r = 0; r < 16; ++r) {
        const int row = (r & 3) + 8 * (r >> 2) + 4 * h;
        red[wv * 1024 + row * 32 + m] = acc[r];
    }
    __syncthreads();

    // ---- reduce 16 waves -> out = sum - U (plain stores, no init needed) ----
    {
        const int row = t >> 5, col = t & 31;
        float s = 0.f;
        #pragma unroll
        for (int w = 0; w < NWAVE; ++w) s += red[w * 1024 + row * 32 + col];
        if (col < CC) {
            const size_t o = (size_t)(ibase + row) * CC + col;
            out[o] = s - U[o];
        }
    }
}

extern "C" void kernel_launch(void* const* d_in, const int* in_sizes, int n_in,
                              void* d_out, int out_size, void* d_ws, size_t ws_size,
                              hipStream_t stream) {
    const float* U   = (const float*)d_in[0];
    const float* ref = (const float*)d_in[1];
    float* out = (float*)d_out;
    char* ws = (char*)d_ws;   // needs 768 KB

    const int pack_threads = NTILE_G * 64 + NTILE_G * 2 * 64;   // 49152
    pack_frags<<<pack_threads / 256, 256, 0, stream>>>(U, ref, ws);
    lattice_main<<<NBLK, MAINT, 0, stream>>>(U, ref, (const char*)ws, out);
}